// Round 2
// baseline (1923.556 us; speedup 1.0000x reference)
//
#include <hip/hip_runtime.h>

// Quantized linear: y[M,N] = x[M,K] @ dequant(W)[N,K]^T + bias
// M=8192 (4*2048), K=4096, N=11008, groups of 128 along K (G=32).
#define M_DIM 8192
#define K_DIM 4096
#define N_DIM 11008
#define NGROUP 32

typedef _Float16 half8 __attribute__((ext_vector_type(8)));
typedef _Float16 half4v __attribute__((ext_vector_type(4)));
typedef float f32x4 __attribute__((ext_vector_type(4)));

typedef const __attribute__((address_space(1))) unsigned int* gas_ptr;
typedef __attribute__((address_space(3))) unsigned int* las_ptr;

__device__ __forceinline__ void gload16(const void* g, void* l) {
  __builtin_amdgcn_global_load_lds((gas_ptr)g, (las_ptr)l, 16, 0, 0);
}

// ---------------- prep 1: split x (fp32) into f16 hi + f16 lo ----------------
__global__ __launch_bounds__(256) void split_x(const float* __restrict__ x,
                                               _Float16* __restrict__ xhi,
                                               _Float16* __restrict__ xlo) {
  const int n4 = (M_DIM * K_DIM) / 4;
  const int stride = gridDim.x * blockDim.x;
  for (int i = blockIdx.x * blockDim.x + threadIdx.x; i < n4; i += stride) {
    float4 v = ((const float4*)x)[i];
    float f0 = v.x, f1 = v.y, f2 = v.z, f3 = v.w;
    half4v hi, lo;
    _Float16 h;
    h = (_Float16)f0; hi[0] = h; lo[0] = (_Float16)(f0 - (float)h);
    h = (_Float16)f1; hi[1] = h; lo[1] = (_Float16)(f1 - (float)h);
    h = (_Float16)f2; hi[2] = h; lo[2] = (_Float16)(f2 - (float)h);
    h = (_Float16)f3; hi[3] = h; lo[3] = (_Float16)(f3 - (float)h);
    ((half4v*)xhi)[i] = hi;
    ((half4v*)xlo)[i] = lo;
  }
}

// ---------------- prep 2: qz = (q - z) exact in f16 ----------------
__global__ __launch_bounds__(256) void dq_codes(const int* __restrict__ qw,
                                                const int* __restrict__ zr,
                                                _Float16* __restrict__ qz) {
  const int n4 = (N_DIM * K_DIM) / 4;
  const int stride = gridDim.x * blockDim.x;
  for (int i = blockIdx.x * blockDim.x + threadIdx.x; i < n4; i += stride) {
    int4 v = ((const int4*)qw)[i];
    int flat = i << 2;               // element index, 4-aligned -> same group
    int o = flat >> 12;              // / 4096
    int gq = (flat & 4095) >> 7;     // (%4096)/128
    int z = zr[o * NGROUP + gq];
    half4v r;
    r[0] = (_Float16)(v.x - z);
    r[1] = (_Float16)(v.y - z);
    r[2] = (_Float16)(v.z - z);
    r[3] = (_Float16)(v.w - z);
    ((half4v*)qz)[i] = r;
  }
}

// ---------------- main GEMM ----------------
// 128x128 tile, BK=64, 256 threads (2x2 waves of 64x64), mfma_f32_16x16x32_f16.
// Per group (2 K-tiles): D accumulates x_hi*qz + x_lo*qz; then y += s[o,g]*D.
template <bool FIRST>
__device__ __forceinline__ void ctile(const _Float16* lAhi, const _Float16* lAlo,
                                      const _Float16* lB, f32x4 (&d)[4][4],
                                      int aB, int bB, int sl0) {
#pragma unroll
  for (int kk = 0; kk < 2; ++kk) {
    const int so = sl0 ^ (kk << 5);  // slot*8 elements, XOR-swizzled
    half8 bf[4];
#pragma unroll
    for (int fn = 0; fn < 4; ++fn)
      bf[fn] = *(const half8*)&lB[bB + fn * 1024 + so];
#pragma unroll
    for (int fm = 0; fm < 4; ++fm) {
      half8 ah = *(const half8*)&lAhi[aB + fm * 1024 + so];
      half8 al = *(const half8*)&lAlo[aB + fm * 1024 + so];
#pragma unroll
      for (int fn = 0; fn < 4; ++fn) {
        f32x4 c0;
        if (FIRST && kk == 0) {
          f32x4 z = {0.f, 0.f, 0.f, 0.f};
          c0 = z;                     // fresh accumulator for this group
        } else {
          c0 = d[fm][fn];
        }
        c0 = __builtin_amdgcn_mfma_f32_16x16x32_f16(ah, bf[fn], c0, 0, 0, 0);
        d[fm][fn] = __builtin_amdgcn_mfma_f32_16x16x32_f16(al, bf[fn], c0, 0, 0, 0);
      }
    }
  }
}

__global__ __launch_bounds__(256, 2) void qlin_gemm(
    const _Float16* __restrict__ xhi, const _Float16* __restrict__ xlo,
    const _Float16* __restrict__ qz, const float* __restrict__ scales,
    const float* __restrict__ bias, float* __restrict__ out) {
  // 16 KB per tile buffer; 64 KB total -> 2 blocks/CU
  __shared__ __align__(16) _Float16 lAhi[128 * 64];
  __shared__ __align__(16) _Float16 lAlo[128 * 64];
  __shared__ __align__(16) _Float16 lB[128 * 64];
  __shared__ float lS[NGROUP * 128];  // s transposed: [g][col]

  const int t = threadIdx.x;
  const int w = t >> 6, l = t & 63;

  // Block order: XCD c (= bid&7) walks mb = c + 8*(seq/86) across all nb.
  // A-slice (2MB) stays L2-resident; B (90MB) L3-resident.
  const int bid = blockIdx.x;
  const int c = bid & 7;
  const int seq = bid >> 3;           // 0..687
  const int mrow = seq / 86;          // 0..7
  const int nb = seq - mrow * 86;     // 0..85
  const int mb = c + mrow * 8;        // 0..63
  const int m0 = mb << 7, n0 = nb << 7;

  // load scales tile into LDS, transposed: lS[g*128 + col]
  for (int i = t; i < NGROUP * 128; i += 256)
    lS[((i & 31) << 7) + (i >> 5)] = scales[n0 * NGROUP + i];

  // staging source addressing (pre-swizzled chunk so LDS dest stays linear)
  const int trow = t >> 3;                              // 0..31
  const int csrc = ((t & 7) ^ (trow & 7)) << 3;         // element offset in row
  const _Float16* gA = xhi + (m0 + trow) * K_DIM + csrc;
  const _Float16* gAl = xlo + (m0 + trow) * K_DIM + csrc;
  const _Float16* gB = qz + (n0 + trow) * K_DIM + csrc;
  const int ldsw = w << 9;  // wave-uniform LDS element base

  // fragment addressing
  const int wm = (w >> 1) << 6, wn = (w & 1) << 6;
  const int lrow = l & 15, lk = l >> 4;
  const int sl0 = (lk ^ (lrow & 7)) << 3;  // kk=0 slot*8
  const int aB = (wm + lrow) << 6;
  const int bB = (wn + lrow) << 6;

  f32x4 d[4][4] = {};
  f32x4 y[4][4] = {};

  auto stage = [&](int k0) {
#pragma unroll
    for (int s = 0; s < 4; ++s) {
      const int lo_ = (s << 11) + ldsw;
      const int go = k0 + (s << 17);  // s*32 rows * 4096
      gload16(gA + go, &lAhi[lo_]);
      gload16(gAl + go, &lAlo[lo_]);
      gload16(gB + go, &lB[lo_]);
    }
  };

#pragma unroll 1
  for (int g = 0; g < 32; ++g) {
    const int k0 = g << 7;
    __syncthreads();
    stage(k0);
    __syncthreads();
    ctile<true>(lAhi, lAlo, lB, d, aB, bB, sl0);
    __syncthreads();
    stage(k0 + 64);
    __syncthreads();
    ctile<false>(lAhi, lAlo, lB, d, aB, bB, sl0);
    // drain: y += s[o,g] * D  (fp32)
#pragma unroll
    for (int fn = 0; fn < 4; ++fn) {
      float sv = lS[(g << 7) + wn + fn * 16 + lrow];
#pragma unroll
      for (int fm = 0; fm < 4; ++fm) y[fm][fn] += d[fm][fn] * sv;
    }
  }

  // epilogue: + bias, store fp32
#pragma unroll
  for (int fn = 0; fn < 4; ++fn) {
    const int col = n0 + wn + fn * 16 + lrow;
    const float bv = bias[col];
#pragma unroll
    for (int fm = 0; fm < 4; ++fm) {
      const int row = m0 + wm + fm * 16 + (lk << 2);
#pragma unroll
      for (int rr = 0; rr < 4; ++rr)
        out[(size_t)(row + rr) * N_DIM + col] = y[fm][fn][rr] + bv;
    }
  }
}

// ---------------- fallback (ws too small): correct tiled fp32 ----------------
__global__ __launch_bounds__(256) void qlin_naive(
    const float* __restrict__ x, const float* __restrict__ scales,
    const float* __restrict__ bias, const int* __restrict__ qw,
    const int* __restrict__ zr, float* __restrict__ out) {
  __shared__ float lx[64 * 128];
  __shared__ float lw[64 * 128];
  const int t = threadIdx.x;
  const int bn = blockIdx.x % 172, bm = blockIdx.x / 172;
  const int m0 = bm << 6, n0 = bn << 6;
  const int tn = (t & 15) << 2, tm = (t >> 4) << 2;
  float acc[4][4] = {};
#pragma unroll 1
  for (int g = 0; g < 32; ++g) {
    const int k0 = g << 7;
    __syncthreads();
    for (int j = 0; j < 32; ++j) {
      int idx = j * 256 + t;
      int r = idx >> 7, cc = idx & 127;
      lx[idx] = x[(size_t)(m0 + r) * K_DIM + k0 + cc];
      float s = scales[(n0 + r) * NGROUP + g];
      float z = (float)zr[(n0 + r) * NGROUP + g];
      lw[idx] = s * ((float)qw[(size_t)(n0 + r) * K_DIM + k0 + cc] - z);
    }
    __syncthreads();
    for (int kk = 0; kk < 128; ++kk) {
      float a[4], b[4];
#pragma unroll
      for (int i = 0; i < 4; ++i) a[i] = lx[(tm + i) * 128 + kk];
#pragma unroll
      for (int j = 0; j < 4; ++j) b[j] = lw[(tn + j) * 128 + kk];
#pragma unroll
      for (int i = 0; i < 4; ++i)
#pragma unroll
        for (int j = 0; j < 4; ++j) acc[i][j] += a[i] * b[j];
    }
  }
#pragma unroll
  for (int i = 0; i < 4; ++i)
#pragma unroll
    for (int j = 0; j < 4; ++j)
      out[(size_t)(m0 + tm + i) * N_DIM + n0 + tn + j] =
          acc[i][j] + bias[n0 + tn + j];
}

extern "C" void kernel_launch(void* const* d_in, const int* in_sizes, int n_in,
                              void* d_out, int out_size, void* d_ws,
                              size_t ws_size, hipStream_t stream) {
  const float* x = (const float*)d_in[0];
  const float* scales = (const float*)d_in[1];
  const float* bias = (const float*)d_in[2];
  const int* qw = (const int*)d_in[3];
  const int* zr = (const int*)d_in[4];
  float* out = (float*)d_out;

  const size_t sz_xhi = (size_t)M_DIM * K_DIM * 2;  // 64 MB
  const size_t sz_qz = (size_t)N_DIM * K_DIM * 2;   // 90 MB
  const size_t need = sz_xhi * 2 + sz_qz;           // 224 MB

  if (ws_size >= need) {
    _Float16* xhi = (_Float16*)d_ws;
    _Float16* xlo = (_Float16*)((char*)d_ws + sz_xhi);
    _Float16* qz = (_Float16*)((char*)d_ws + 2 * sz_xhi);
    split_x<<<2048, 256, 0, stream>>>(x, xhi, xlo);
    dq_codes<<<2048, 256, 0, stream>>>(qw, zr, qz);
    qlin_gemm<<<(M_DIM / 128) * (N_DIM / 128), 256, 0, stream>>>(
        xhi, xlo, qz, scales, bias, out);
  } else {
    qlin_naive<<<(M_DIM / 64) * (N_DIM / 64), 256, 0, stream>>>(
        x, scales, bias, qw, zr, out);
  }
}